// Round 1
// baseline (1107.608 us; speedup 1.0000x reference)
//
#include <hip/hip_runtime.h>
#include <math.h>

#define N_NODES_DIV_CHECK 128
#define D 128
#define LN_EPS 1e-5f

// ---------------- graph build ----------------

__global__ __launch_bounds__(256) void degree_kernel(const int* __restrict__ ei, int E,
                                                     int* __restrict__ deg) {
    int e = blockIdx.x * 256 + threadIdx.x;
    if (e >= E) return;
    int d = ei[E + e];
    atomicAdd(&deg[d], 1);
}

// single-block exclusive scan over deg[0..n-1] -> row_ptr[0..n]
__global__ __launch_bounds__(1024) void scan_kernel(const int* __restrict__ deg,
                                                    int* __restrict__ row_ptr, int n) {
    __shared__ int wave_tot[16];
    const int lane = threadIdx.x & 63;
    const int wid = threadIdx.x >> 6;
    int running = 0;
    for (int base = 0; base < n; base += 1024) {
        int i = base + (int)threadIdx.x;
        int v = (i < n) ? deg[i] : 0;
        // wave-level inclusive scan
        int incl = v;
        #pragma unroll
        for (int off = 1; off < 64; off <<= 1) {
            int t = __shfl_up(incl, off, 64);
            if (lane >= off) incl += t;
        }
        if (lane == 63) wave_tot[wid] = incl;
        __syncthreads();
        int prefix = running;
        for (int w = 0; w < wid; ++w) prefix += wave_tot[w];
        if (i < n) row_ptr[i] = prefix + incl - v;  // exclusive
        int total = 0;
        for (int w = 0; w < 16; ++w) total += wave_tot[w];
        __syncthreads();
        running += total;
    }
    if (threadIdx.x == 0) row_ptr[n] = running;
}

__global__ __launch_bounds__(256) void fill_csr_kernel(const int* __restrict__ ei, int E,
                                                       const int* __restrict__ row_ptr,
                                                       int* __restrict__ cursor,
                                                       int* __restrict__ csr_src) {
    int e = blockIdx.x * 256 + threadIdx.x;
    if (e >= E) return;
    int s = ei[e];
    int d = ei[E + e];
    int pos = row_ptr[d] + atomicAdd(&cursor[d], 1);
    csr_src[pos] = s;
}

// ---------------- aggregation (CSR gather, mean) ----------------
// 32 lanes per node (each lane owns a float4 of the 128-dim row), 8 nodes/block.
__global__ __launch_bounds__(256) void aggregate_kernel(const float* __restrict__ h,
                                                        const int* __restrict__ row_ptr,
                                                        const int* __restrict__ csr_src,
                                                        float* __restrict__ agg, int n) {
    int node = blockIdx.x * 8 + (threadIdx.x >> 5);
    int lane = threadIdx.x & 31;
    if (node >= n) return;
    int s0 = row_ptr[node];
    int s1 = row_ptr[node + 1];
    float4 acc = make_float4(0.f, 0.f, 0.f, 0.f);
    for (int e = s0; e < s1; ++e) {
        int src = csr_src[e];
        const float4 v = *(const float4*)&h[(size_t)src * D + lane * 4];
        acc.x += v.x; acc.y += v.y; acc.z += v.z; acc.w += v.w;
    }
    int dg = s1 - s0;
    float sc = (dg > 0) ? (1.0f / (float)dg) : 0.0f;
    acc.x *= sc; acc.y *= sc; acc.z *= sc; acc.w *= sc;
    *(float4*)&agg[(size_t)node * D + lane * 4] = acc;
}

// ---------------- fused SAGE layer GEMM ----------------
// out[n][j] = silu( LN( sum_k agg[n][k]*Wl[j][k] + hin[n][k]*Wr[j][k] + bl[j]+br[j] ) )
// Tile: 64 nodes x 128 outputs per block (256 threads), K = 256 (two 128 halves),
// K-chunks of 32 staged in LDS. Per-thread micro-tile 4n x 8j.
__global__ __launch_bounds__(256) void sage_layer_kernel(
    const float* __restrict__ agg, const float* __restrict__ hin,
    const float* __restrict__ Wl, const float* __restrict__ Wr,
    const float* __restrict__ bl, const float* __restrict__ br,
    const float* __restrict__ lng, const float* __restrict__ lnb,
    float* __restrict__ hout, int n) {
    __shared__ float w_t[32][132];  // [k][j], padded
    __shared__ float a_t[32][68];   // [k][n], padded

    const int tid = threadIdx.x;
    const int n0 = blockIdx.x * 64;
    const int jt = (tid & 15) * 8;
    const int nt = (tid >> 4) * 4;

    float acc[4][8] = {};

    for (int c = 0; c < 8; ++c) {
        const int kb = (c & 3) * 32;
        const float* __restrict__ Wp = (c < 4) ? Wl : Wr;
        const float* __restrict__ Ap = (c < 4) ? agg : hin;
        __syncthreads();
        // stage W chunk: 32k x 128j  (coalesced along k)
        #pragma unroll
        for (int p = 0; p < 16; ++p) {
            int idx = p * 256 + tid;
            int kk = idx & 31, j = idx >> 5;
            w_t[kk][j] = Wp[j * D + kb + kk];
        }
        // stage act chunk: 32k x 64n
        #pragma unroll
        for (int p = 0; p < 8; ++p) {
            int idx = p * 256 + tid;
            int kk = idx & 31, nl = idx >> 5;
            int nn = n0 + nl;
            a_t[kk][nl] = (nn < n) ? Ap[(size_t)nn * D + kb + kk] : 0.0f;
        }
        __syncthreads();
        #pragma unroll
        for (int kk = 0; kk < 32; ++kk) {
            float4 av = *(const float4*)&a_t[kk][nt];
            float4 w0 = *(const float4*)&w_t[kk][jt];
            float4 w1 = *(const float4*)&w_t[kk][jt + 4];
            float a[4] = {av.x, av.y, av.z, av.w};
            float w[8] = {w0.x, w0.y, w0.z, w0.w, w1.x, w1.y, w1.z, w1.w};
            #pragma unroll
            for (int ni = 0; ni < 4; ++ni)
                #pragma unroll
                for (int jj = 0; jj < 8; ++jj)
                    acc[ni][jj] += a[ni] * w[jj];
        }
    }

    // epilogue: bias + LayerNorm + SiLU
    float bsum[8], g[8], bb[8];
    #pragma unroll
    for (int jj = 0; jj < 8; ++jj) {
        bsum[jj] = bl[jt + jj] + br[jt + jj];
        g[jj] = lng[jt + jj];
        bb[jj] = lnb[jt + jj];
    }
    #pragma unroll
    for (int ni = 0; ni < 4; ++ni) {
        float s = 0.f, s2 = 0.f;
        #pragma unroll
        for (int jj = 0; jj < 8; ++jj) {
            float v = acc[ni][jj] + bsum[jj];
            acc[ni][jj] = v;
            s += v; s2 += v * v;
        }
        // reduce across the 16 lanes (lane bits 0..3) that hold this row
        #pragma unroll
        for (int off = 1; off < 16; off <<= 1) {
            s += __shfl_xor(s, off, 64);
            s2 += __shfl_xor(s2, off, 64);
        }
        float mean = s * (1.0f / 128.0f);
        float var = s2 * (1.0f / 128.0f) - mean * mean;
        float rstd = rsqrtf(var + LN_EPS);
        float vals[8];
        #pragma unroll
        for (int jj = 0; jj < 8; ++jj) {
            float z = (acc[ni][jj] - mean) * rstd * g[jj] + bb[jj];
            vals[jj] = z / (1.0f + expf(-z));  // SiLU
        }
        int nn = n0 + nt + ni;
        if (nn < n) {
            float4 v0 = make_float4(vals[0], vals[1], vals[2], vals[3]);
            float4 v1 = make_float4(vals[4], vals[5], vals[6], vals[7]);
            *(float4*)&hout[(size_t)nn * D + jt] = v0;
            *(float4*)&hout[(size_t)nn * D + jt + 4] = v1;
        }
    }
}

// ---------------- fused MLP head ----------------
// out[n] = b2 + sum_j w2[j] * relu( b1[j] + sum_k hin[n][k]*W1[j][k] )
__global__ __launch_bounds__(256) void mlp_head_kernel(
    const float* __restrict__ hin, const float* __restrict__ W1,
    const float* __restrict__ b1, const float* __restrict__ w2,
    const float* __restrict__ b2, float* __restrict__ out, int n) {
    __shared__ float w_t[32][132];
    __shared__ float a_t[32][68];

    const int tid = threadIdx.x;
    const int n0 = blockIdx.x * 64;
    const int jt = (tid & 15) * 8;
    const int nt = (tid >> 4) * 4;

    float acc[4][8] = {};

    for (int c = 0; c < 4; ++c) {
        const int kb = c * 32;
        __syncthreads();
        #pragma unroll
        for (int p = 0; p < 16; ++p) {
            int idx = p * 256 + tid;
            int kk = idx & 31, j = idx >> 5;
            w_t[kk][j] = W1[j * D + kb + kk];
        }
        #pragma unroll
        for (int p = 0; p < 8; ++p) {
            int idx = p * 256 + tid;
            int kk = idx & 31, nl = idx >> 5;
            int nn = n0 + nl;
            a_t[kk][nl] = (nn < n) ? hin[(size_t)nn * D + kb + kk] : 0.0f;
        }
        __syncthreads();
        #pragma unroll
        for (int kk = 0; kk < 32; ++kk) {
            float4 av = *(const float4*)&a_t[kk][nt];
            float4 w0 = *(const float4*)&w_t[kk][jt];
            float4 w1 = *(const float4*)&w_t[kk][jt + 4];
            float a[4] = {av.x, av.y, av.z, av.w};
            float w[8] = {w0.x, w0.y, w0.z, w0.w, w1.x, w1.y, w1.z, w1.w};
            #pragma unroll
            for (int ni = 0; ni < 4; ++ni)
                #pragma unroll
                for (int jj = 0; jj < 8; ++jj)
                    acc[ni][jj] += a[ni] * w[jj];
        }
    }

    float bias1[8], wv2[8];
    #pragma unroll
    for (int jj = 0; jj < 8; ++jj) {
        bias1[jj] = b1[jt + jj];
        wv2[jj] = w2[jt + jj];
    }
    float b2v = b2[0];
    #pragma unroll
    for (int ni = 0; ni < 4; ++ni) {
        float p = 0.f;
        #pragma unroll
        for (int jj = 0; jj < 8; ++jj) {
            float v = acc[ni][jj] + bias1[jj];
            v = fmaxf(v, 0.0f);
            p += v * wv2[jj];
        }
        #pragma unroll
        for (int off = 1; off < 16; off <<= 1) p += __shfl_xor(p, off, 64);
        if ((tid & 15) == 0) {
            int nn = n0 + nt + ni;
            if (nn < n) out[nn] = p + b2v;
        }
    }
}

// ---------------- launch ----------------

static inline size_t align_up(size_t v, size_t a) { return (v + a - 1) & ~(a - 1); }

extern "C" void kernel_launch(void* const* d_in, const int* in_sizes, int n_in,
                              void* d_out, int out_size, void* d_ws, size_t ws_size,
                              hipStream_t stream) {
    const float* x       = (const float*)d_in[0];
    const int*   ei      = (const int*)d_in[1];
    const float* lin_l_w = (const float*)d_in[2];
    const float* lin_l_b = (const float*)d_in[3];
    const float* lin_r_w = (const float*)d_in[4];
    const float* lin_r_b = (const float*)d_in[5];
    const float* ln_g    = (const float*)d_in[6];
    const float* ln_b    = (const float*)d_in[7];
    const float* mlp_w1  = (const float*)d_in[8];
    const float* mlp_b1  = (const float*)d_in[9];
    const float* mlp_w2  = (const float*)d_in[10];
    const float* mlp_b2  = (const float*)d_in[11];
    float* out = (float*)d_out;

    const int N = in_sizes[0] / D;   // 100000
    const int E = in_sizes[1] / 2;   // 1600000

    // workspace layout
    char* w = (char*)d_ws;
    size_t off = 0;
    int* deg = (int*)(w + off);        off = align_up(off + sizeof(int) * (size_t)N, 512);
    int* row_ptr = (int*)(w + off);    off = align_up(off + sizeof(int) * (size_t)(N + 1), 512);
    int* cursor = (int*)(w + off);     off = align_up(off + sizeof(int) * (size_t)N, 512);
    int* csr_src = (int*)(w + off);    off = align_up(off + sizeof(int) * (size_t)E, 512);
    float* aggb = (float*)(w + off);   off = align_up(off + sizeof(float) * (size_t)N * D, 512);
    float* bufA = (float*)(w + off);   off = align_up(off + sizeof(float) * (size_t)N * D, 512);
    float* bufB = (float*)(w + off);   off = align_up(off + sizeof(float) * (size_t)N * D, 512);

    // graph build (must redo every call; ws is re-poisoned)
    hipMemsetAsync(deg, 0, sizeof(int) * (size_t)N, stream);
    hipMemsetAsync(cursor, 0, sizeof(int) * (size_t)N, stream);
    degree_kernel<<<(E + 255) / 256, 256, 0, stream>>>(ei, E, deg);
    scan_kernel<<<1, 1024, 0, stream>>>(deg, row_ptr, N);
    fill_csr_kernel<<<(E + 255) / 256, 256, 0, stream>>>(ei, E, row_ptr, cursor, csr_src);

    const int gemm_grid = (N + 63) / 64;
    const int agg_grid = (N + 7) / 8;

    // layer 0
    aggregate_kernel<<<agg_grid, 256, 0, stream>>>(x, row_ptr, csr_src, aggb, N);
    sage_layer_kernel<<<gemm_grid, 256, 0, stream>>>(
        aggb, x, lin_l_w, lin_r_w, lin_l_b, lin_r_b, ln_g, ln_b, bufA, N);
    // layer 1
    aggregate_kernel<<<agg_grid, 256, 0, stream>>>(bufA, row_ptr, csr_src, aggb, N);
    sage_layer_kernel<<<gemm_grid, 256, 0, stream>>>(
        aggb, bufA, lin_l_w + D * D, lin_r_w + D * D, lin_l_b + D, lin_r_b + D,
        ln_g + D, ln_b + D, bufB, N);
    // head
    mlp_head_kernel<<<gemm_grid, 256, 0, stream>>>(bufB, mlp_w1, mlp_b1, mlp_w2, mlp_b2, out, N);
}

// Round 2
// 673.030 us; speedup vs baseline: 1.6457x; 1.6457x over previous
//
#include <hip/hip_runtime.h>
#include <math.h>

#define D 128
#define LN_EPS 1e-5f

typedef unsigned short ushort_t;
typedef unsigned int uint_t;
typedef __attribute__((ext_vector_type(8))) short bf16x8;
typedef __attribute__((ext_vector_type(8))) unsigned short u16x8;
typedef __attribute__((ext_vector_type(4))) float f32x4;

static __device__ __forceinline__ float bf2f(ushort_t u) {
    union { uint_t i; float f; } c; c.i = ((uint_t)u) << 16; return c.f;
}
static __device__ __forceinline__ ushort_t f2bf(float f) {
    union { float f; uint_t i; } c; c.f = f;
    uint_t u = c.i;
    uint_t r = (u + 0x7fffu + ((u >> 16) & 1u)) >> 16;   // RNE
    return (ushort_t)r;
}

// ---------------- casts ----------------
__global__ __launch_bounds__(256) void cast_f32_bf16(const float* __restrict__ in,
                                                     ushort_t* __restrict__ out, int n) {
    int i = (blockIdx.x * 256 + threadIdx.x) * 8;
    if (i + 8 > n) return;
    float4 a = *(const float4*)&in[i];
    float4 b = *(const float4*)&in[i + 4];
    u16x8 v;
    v[0] = f2bf(a.x); v[1] = f2bf(a.y); v[2] = f2bf(a.z); v[3] = f2bf(a.w);
    v[4] = f2bf(b.x); v[5] = f2bf(b.y); v[6] = f2bf(b.z); v[7] = f2bf(b.w);
    *(u16x8*)&out[i] = v;
}

// ---------------- graph build ----------------
__global__ __launch_bounds__(256) void degree_kernel(const int* __restrict__ ei, int E,
                                                     int* __restrict__ deg) {
    int e = blockIdx.x * 256 + threadIdx.x;
    if (e >= E) return;
    atomicAdd(&deg[ei[E + e]], 1);
}

__global__ __launch_bounds__(1024) void scan_kernel(const int* __restrict__ deg,
                                                    int* __restrict__ row_ptr, int n) {
    __shared__ int wave_tot[16];
    const int lane = threadIdx.x & 63;
    const int wid = threadIdx.x >> 6;
    int running = 0;
    for (int base = 0; base < n; base += 1024) {
        int i = base + (int)threadIdx.x;
        int v = (i < n) ? deg[i] : 0;
        int incl = v;
        #pragma unroll
        for (int off = 1; off < 64; off <<= 1) {
            int t = __shfl_up(incl, off, 64);
            if (lane >= off) incl += t;
        }
        if (lane == 63) wave_tot[wid] = incl;
        __syncthreads();
        int prefix = running;
        for (int w = 0; w < wid; ++w) prefix += wave_tot[w];
        if (i < n) row_ptr[i] = prefix + incl - v;
        int total = 0;
        for (int w = 0; w < 16; ++w) total += wave_tot[w];
        __syncthreads();
        running += total;
    }
    if (threadIdx.x == 0) row_ptr[n] = running;
}

__global__ __launch_bounds__(256) void fill_csr_kernel(const int* __restrict__ ei, int E,
                                                       const int* __restrict__ row_ptr,
                                                       int* __restrict__ cursor,
                                                       int* __restrict__ csr_src) {
    int e = blockIdx.x * 256 + threadIdx.x;
    if (e >= E) return;
    int s = ei[e];
    int d = ei[E + e];
    int pos = row_ptr[d] + atomicAdd(&cursor[d], 1);
    csr_src[pos] = s;
}

// ---------------- aggregation (bf16 gather, fp32 accum, bf16 out) ----------------
// 16 lanes per node; each lane owns 8 cols (16 B). 16 nodes / block.
__global__ __launch_bounds__(256) void aggregate_bf16(const ushort_t* __restrict__ h,
                                                      const int* __restrict__ row_ptr,
                                                      const int* __restrict__ csr_src,
                                                      ushort_t* __restrict__ agg, int n) {
    int node = blockIdx.x * 16 + (threadIdx.x >> 4);
    int lane = threadIdx.x & 15;
    if (node >= n) return;
    int s0 = row_ptr[node];
    int s1 = row_ptr[node + 1];
    float acc[8] = {0.f, 0.f, 0.f, 0.f, 0.f, 0.f, 0.f, 0.f};
    int e = s0;
    int src = (e < s1) ? csr_src[e] : 0;
    while (e < s1) {
        int nxt = (e + 1 < s1) ? csr_src[e + 1] : 0;
        u16x8 v = *(const u16x8*)&h[(size_t)src * D + lane * 8];
        #pragma unroll
        for (int i = 0; i < 8; ++i) acc[i] += bf2f(v[i]);
        src = nxt;
        ++e;
    }
    int dg = s1 - s0;
    float sc = (dg > 0) ? (1.0f / (float)dg) : 0.0f;
    u16x8 o;
    #pragma unroll
    for (int i = 0; i < 8; ++i) o[i] = f2bf(acc[i] * sc);
    *(u16x8*)&agg[(size_t)node * D + lane * 8] = o;
}

// ---------------- fused SAGE layer: MFMA GEMM + bias + LN + SiLU ----------------
// Block: 256 threads = 4 waves; each wave computes 16 rows x 128 cols.
// K = 256 (agg:0..127 via Wl, hin:0..127 via Wr), 8 chunks of 32.
// A and B fragments loaded DIRECTLY from global in MFMA layout (no LDS staging).
__global__ __launch_bounds__(256) void sage_mfma(
    const ushort_t* __restrict__ agg, const ushort_t* __restrict__ hin,
    const ushort_t* __restrict__ Wl, const ushort_t* __restrict__ Wr,
    const float* __restrict__ bl, const float* __restrict__ br,
    const float* __restrict__ lng, const float* __restrict__ lnb,
    ushort_t* __restrict__ hout, int n) {
    __shared__ ushort_t tile[64][132];   // stride 132 -> conflict-free b16 writes

    const int tid = threadIdx.x;
    const int wave = tid >> 6;
    const int lane = tid & 63;
    const int quad = lane >> 4;       // 0..3
    const int l16 = lane & 15;
    const int n0w = blockIdx.x * 64 + wave * 16;

    int arow = n0w + l16;
    if (arow >= n) arow = n - 1;      // clamp; invalid rows never written out

    f32x4 acc[8];
    #pragma unroll
    for (int jt = 0; jt < 8; ++jt) acc[jt] = (f32x4){0.f, 0.f, 0.f, 0.f};

    #pragma unroll
    for (int c = 0; c < 8; ++c) {
        const ushort_t* __restrict__ act = (c < 4) ? agg : hin;
        const ushort_t* __restrict__ W = (c < 4) ? Wl : Wr;
        const int kb = (c & 3) * 32;
        bf16x8 afrag = *(const bf16x8*)&act[(size_t)arow * D + kb + quad * 8];
        #pragma unroll
        for (int jt = 0; jt < 8; ++jt) {
            bf16x8 bfrag = *(const bf16x8*)&W[(size_t)(jt * 16 + l16) * D + kb + quad * 8];
            acc[jt] = __builtin_amdgcn_mfma_f32_16x16x32_bf16(afrag, bfrag, acc[jt], 0, 0, 0);
        }
    }

    // epilogue: bias + LayerNorm + SiLU, write bf16 rows via LDS
    float bsum[8], g[8], bb[8];
    #pragma unroll
    for (int jt = 0; jt < 8; ++jt) {
        int j = jt * 16 + l16;
        bsum[jt] = bl[j] + br[j];
        g[jt] = lng[j];
        bb[jt] = lnb[j];
    }
    #pragma unroll
    for (int r = 0; r < 4; ++r) {
        float v[8];
        float s = 0.f, s2 = 0.f;
        #pragma unroll
        for (int jt = 0; jt < 8; ++jt) {
            float t = acc[jt][r] + bsum[jt];
            v[jt] = t;
            s += t; s2 += t * t;
        }
        #pragma unroll
        for (int off = 1; off < 16; off <<= 1) {
            s += __shfl_xor(s, off, 64);
            s2 += __shfl_xor(s2, off, 64);
        }
        float mean = s * (1.0f / 128.0f);
        float var = s2 * (1.0f / 128.0f) - mean * mean;
        float rstd = rsqrtf(var + LN_EPS);
        int rowb = wave * 16 + quad * 4 + r;
        #pragma unroll
        for (int jt = 0; jt < 8; ++jt) {
            float z = (v[jt] - mean) * rstd * g[jt] + bb[jt];
            float sv = z / (1.0f + expf(-z));
            tile[rowb][jt * 16 + l16] = f2bf(sv);
        }
    }
    __syncthreads();
    // coalesced bf16 write-out: thread t -> row t>>2, 32-col segment t&3
    int row = tid >> 2, seg = tid & 3;
    int node = blockIdx.x * 64 + row;
    if (node < n) {
        #pragma unroll
        for (int k2 = 0; k2 < 4; ++k2) {
            u16x8 vv = *(const u16x8*)&tile[row][seg * 32 + k2 * 8];
            *(u16x8*)&hout[(size_t)node * D + seg * 32 + k2 * 8] = vv;
        }
    }
}

// ---------------- fused MLP head: MFMA GEMM + bias + ReLU + dot(w2) + b2 ----------------
__global__ __launch_bounds__(256) void mlp_head_mfma(
    const ushort_t* __restrict__ hin, const ushort_t* __restrict__ W1,
    const float* __restrict__ b1, const float* __restrict__ w2,
    const float* __restrict__ b2, float* __restrict__ out, int n) {
    const int tid = threadIdx.x;
    const int wave = tid >> 6;
    const int lane = tid & 63;
    const int quad = lane >> 4;
    const int l16 = lane & 15;
    const int n0w = blockIdx.x * 64 + wave * 16;

    int arow = n0w + l16;
    if (arow >= n) arow = n - 1;

    f32x4 acc[8];
    #pragma unroll
    for (int jt = 0; jt < 8; ++jt) acc[jt] = (f32x4){0.f, 0.f, 0.f, 0.f};

    #pragma unroll
    for (int c = 0; c < 4; ++c) {
        const int kb = c * 32;
        bf16x8 afrag = *(const bf16x8*)&hin[(size_t)arow * D + kb + quad * 8];
        #pragma unroll
        for (int jt = 0; jt < 8; ++jt) {
            bf16x8 bfrag = *(const bf16x8*)&W1[(size_t)(jt * 16 + l16) * D + kb + quad * 8];
            acc[jt] = __builtin_amdgcn_mfma_f32_16x16x32_bf16(afrag, bfrag, acc[jt], 0, 0, 0);
        }
    }

    float bias1[8], wv2[8];
    #pragma unroll
    for (int jt = 0; jt < 8; ++jt) {
        int j = jt * 16 + l16;
        bias1[jt] = b1[j];
        wv2[jt] = w2[j];
    }
    float b2v = b2[0];
    #pragma unroll
    for (int r = 0; r < 4; ++r) {
        float p = 0.f;
        #pragma unroll
        for (int jt = 0; jt < 8; ++jt) {
            float v = acc[jt][r] + bias1[jt];
            v = fmaxf(v, 0.0f);
            p += v * wv2[jt];
        }
        #pragma unroll
        for (int off = 1; off < 16; off <<= 1) p += __shfl_xor(p, off, 64);
        if (l16 == 0) {
            int node = n0w + quad * 4 + r;
            if (node < n) out[node] = p + b2v;
        }
    }
}

// ---------------- launch ----------------
static inline size_t align_up(size_t v, size_t a) { return (v + a - 1) & ~(a - 1); }

extern "C" void kernel_launch(void* const* d_in, const int* in_sizes, int n_in,
                              void* d_out, int out_size, void* d_ws, size_t ws_size,
                              hipStream_t stream) {
    const float* x       = (const float*)d_in[0];
    const int*   ei      = (const int*)d_in[1];
    const float* lin_l_w = (const float*)d_in[2];
    const float* lin_l_b = (const float*)d_in[3];
    const float* lin_r_w = (const float*)d_in[4];
    const float* lin_r_b = (const float*)d_in[5];
    const float* ln_g    = (const float*)d_in[6];
    const float* ln_b    = (const float*)d_in[7];
    const float* mlp_w1  = (const float*)d_in[8];
    const float* mlp_b1  = (const float*)d_in[9];
    const float* mlp_w2  = (const float*)d_in[10];
    const float* mlp_b2  = (const float*)d_in[11];
    float* out = (float*)d_out;

    const int N = in_sizes[0] / D;   // 100000
    const int E = in_sizes[1] / 2;   // 1600000

    // workspace layout
    char* w = (char*)d_ws;
    size_t off = 0;
    int* deg = (int*)(w + off);        off = align_up(off + sizeof(int) * (size_t)N, 512);
    int* row_ptr = (int*)(w + off);    off = align_up(off + sizeof(int) * (size_t)(N + 1), 512);
    int* cursor = (int*)(w + off);     off = align_up(off + sizeof(int) * (size_t)N, 512);
    int* csr_src = (int*)(w + off);    off = align_up(off + sizeof(int) * (size_t)E, 512);
    ushort_t* x_bf = (ushort_t*)(w + off);   off = align_up(off + 2ull * N * D, 512);
    ushort_t* h1_bf = (ushort_t*)(w + off);  off = align_up(off + 2ull * N * D, 512);
    ushort_t* h2_bf = (ushort_t*)(w + off);  off = align_up(off + 2ull * N * D, 512);
    ushort_t* agg_bf = (ushort_t*)(w + off); off = align_up(off + 2ull * N * D, 512);
    ushort_t* wl_bf = (ushort_t*)(w + off);  off = align_up(off + 2ull * 2 * D * D, 512);
    ushort_t* wr_bf = (ushort_t*)(w + off);  off = align_up(off + 2ull * 2 * D * D, 512);
    ushort_t* w1_bf = (ushort_t*)(w + off);  off = align_up(off + 2ull * D * D, 512);

    hipMemsetAsync(deg, 0, sizeof(int) * (size_t)N, stream);
    hipMemsetAsync(cursor, 0, sizeof(int) * (size_t)N, stream);

    // weight + input casts (bf16)
    cast_f32_bf16<<<(2 * D * D) / (8 * 256), 256, 0, stream>>>(lin_l_w, wl_bf, 2 * D * D);
    cast_f32_bf16<<<(2 * D * D) / (8 * 256), 256, 0, stream>>>(lin_r_w, wr_bf, 2 * D * D);
    cast_f32_bf16<<<(D * D + 8 * 256 - 1) / (8 * 256), 256, 0, stream>>>(mlp_w1, w1_bf, D * D);
    cast_f32_bf16<<<(N * D) / (8 * 256), 256, 0, stream>>>(x, x_bf, N * D);

    // graph build
    degree_kernel<<<(E + 255) / 256, 256, 0, stream>>>(ei, E, deg);
    scan_kernel<<<1, 1024, 0, stream>>>(deg, row_ptr, N);
    fill_csr_kernel<<<(E + 255) / 256, 256, 0, stream>>>(ei, E, row_ptr, cursor, csr_src);

    const int gemm_grid = (N + 63) / 64;
    const int agg_grid = (N + 15) / 16;

    // layer 0
    aggregate_bf16<<<agg_grid, 256, 0, stream>>>(x_bf, row_ptr, csr_src, agg_bf, N);
    sage_mfma<<<gemm_grid, 256, 0, stream>>>(
        agg_bf, x_bf, wl_bf, wr_bf, lin_l_b, lin_r_b, ln_g, ln_b, h1_bf, N);
    // layer 1
    aggregate_bf16<<<agg_grid, 256, 0, stream>>>(h1_bf, row_ptr, csr_src, agg_bf, N);
    sage_mfma<<<gemm_grid, 256, 0, stream>>>(
        agg_bf, h1_bf, wl_bf + D * D, wr_bf + D * D, lin_l_b + D, lin_r_b + D,
        ln_g + D, ln_b + D, h2_bf, N);
    // head
    mlp_head_mfma<<<gemm_grid, 256, 0, stream>>>(h2_bf, w1_bf, mlp_b1, mlp_w2, mlp_b2, out, N);
}

// Round 3
// 576.006 us; speedup vs baseline: 1.9229x; 1.1684x over previous
//
#include <hip/hip_runtime.h>
#include <math.h>

#define D 128
#define LN_EPS 1e-5f

#define SCAN_ITEMS 8
#define SCAN_BLOCK 256
#define SCAN_CHUNK (SCAN_ITEMS * SCAN_BLOCK)   // 2048 elements per block

typedef unsigned short ushort_t;
typedef unsigned int uint_t;
typedef __attribute__((ext_vector_type(8))) short bf16x8;
typedef __attribute__((ext_vector_type(8))) unsigned short u16x8;
typedef __attribute__((ext_vector_type(4))) float f32x4;

static __device__ __forceinline__ float bf2f(ushort_t u) {
    union { uint_t i; float f; } c; c.i = ((uint_t)u) << 16; return c.f;
}
static __device__ __forceinline__ ushort_t f2bf(float f) {
    union { float f; uint_t i; } c; c.f = f;
    uint_t u = c.i;
    uint_t r = (u + 0x7fffu + ((u >> 16) & 1u)) >> 16;   // RNE
    return (ushort_t)r;
}

// ---------------- casts ----------------
__global__ __launch_bounds__(256) void cast_f32_bf16(const float* __restrict__ in,
                                                     ushort_t* __restrict__ out, int n) {
    int i = (blockIdx.x * 256 + threadIdx.x) * 8;
    if (i + 8 > n) return;
    float4 a = *(const float4*)&in[i];
    float4 b = *(const float4*)&in[i + 4];
    u16x8 v;
    v[0] = f2bf(a.x); v[1] = f2bf(a.y); v[2] = f2bf(a.z); v[3] = f2bf(a.w);
    v[4] = f2bf(b.x); v[5] = f2bf(b.y); v[6] = f2bf(b.z); v[7] = f2bf(b.w);
    *(u16x8*)&out[i] = v;
}

// ---------------- graph build ----------------
__global__ __launch_bounds__(256) void degree_kernel(const int* __restrict__ ei, int E,
                                                     int* __restrict__ deg) {
    int e = blockIdx.x * 256 + threadIdx.x;
    if (e >= E) return;
    atomicAdd(&deg[ei[E + e]], 1);
}

// hierarchical exclusive scan: pass 1 — per-block sums
__global__ __launch_bounds__(SCAN_BLOCK) void block_sum_kernel(const int* __restrict__ deg,
                                                               int* __restrict__ blk_sums, int n) {
    int base = blockIdx.x * SCAN_CHUNK + threadIdx.x * SCAN_ITEMS;
    int s = 0;
    #pragma unroll
    for (int i = 0; i < SCAN_ITEMS; ++i) {
        int idx = base + i;
        if (idx < n) s += deg[idx];
    }
    #pragma unroll
    for (int off = 1; off < 64; off <<= 1) s += __shfl_xor(s, off, 64);
    __shared__ int ws[4];
    if ((threadIdx.x & 63) == 0) ws[threadIdx.x >> 6] = s;
    __syncthreads();
    if (threadIdx.x == 0) blk_sums[blockIdx.x] = ws[0] + ws[1] + ws[2] + ws[3];
}

// pass 2 — single-block exclusive scan of block sums (nb <= 1024); writes row_ptr[n]=total
__global__ __launch_bounds__(1024) void scan_sums_kernel(int* __restrict__ blk_sums, int nb,
                                                         int* __restrict__ row_ptr, int n) {
    __shared__ int wt[16];
    int i = threadIdx.x;
    int v = (i < nb) ? blk_sums[i] : 0;
    int lane = i & 63, wid = i >> 6;
    int incl = v;
    #pragma unroll
    for (int off = 1; off < 64; off <<= 1) {
        int t = __shfl_up(incl, off, 64);
        if (lane >= off) incl += t;
    }
    if (lane == 63) wt[wid] = incl;
    __syncthreads();
    int prefix = 0;
    for (int w = 0; w < wid; ++w) prefix += wt[w];
    if (i < nb) blk_sums[i] = prefix + incl - v;   // exclusive block offsets, in place
    if (i == 0) {
        int tot = 0;
        for (int w = 0; w < 16; ++w) tot += wt[w];
        row_ptr[n] = tot;
    }
}

// pass 3 — per-block local exclusive scan + block offset
__global__ __launch_bounds__(SCAN_BLOCK) void scan_chunk_kernel(const int* __restrict__ deg,
                                                                const int* __restrict__ blk_offs,
                                                                int* __restrict__ row_ptr, int n) {
    int base = blockIdx.x * SCAN_CHUNK + threadIdx.x * SCAN_ITEMS;
    int vals[SCAN_ITEMS];
    int s = 0;
    #pragma unroll
    for (int i = 0; i < SCAN_ITEMS; ++i) {
        int idx = base + i;
        int v = (idx < n) ? deg[idx] : 0;
        vals[i] = s;
        s += v;
    }
    int lane = threadIdx.x & 63, wid = threadIdx.x >> 6;
    int incl = s;
    #pragma unroll
    for (int off = 1; off < 64; off <<= 1) {
        int t = __shfl_up(incl, off, 64);
        if (lane >= off) incl += t;
    }
    __shared__ int wt[4];
    if (lane == 63) wt[wid] = incl;
    __syncthreads();
    int prefix = 0;
    for (int w = 0; w < wid; ++w) prefix += wt[w];
    int texcl = prefix + incl - s + blk_offs[blockIdx.x];
    #pragma unroll
    for (int i = 0; i < SCAN_ITEMS; ++i) {
        int idx = base + i;
        if (idx < n) row_ptr[idx] = texcl + vals[i];
    }
}

__global__ __launch_bounds__(256) void fill_csr_kernel(const int* __restrict__ ei, int E,
                                                       const int* __restrict__ row_ptr,
                                                       int* __restrict__ cursor,
                                                       int* __restrict__ csr_src) {
    int e = blockIdx.x * 256 + threadIdx.x;
    if (e >= E) return;
    int s = ei[e];
    int d = ei[E + e];
    int pos = row_ptr[d] + atomicAdd(&cursor[d], 1);
    csr_src[pos] = s;
}

// ---------------- aggregation (bf16 gather, fp32 accum, bf16 out) ----------------
// 16 lanes per node; each lane owns 8 cols (16 B). 16 nodes / block.
// Edge loop unrolled x4 for memory-level parallelism.
__global__ __launch_bounds__(256) void aggregate_bf16(const ushort_t* __restrict__ h,
                                                      const int* __restrict__ row_ptr,
                                                      const int* __restrict__ csr_src,
                                                      ushort_t* __restrict__ agg, int n) {
    int node = blockIdx.x * 16 + (threadIdx.x >> 4);
    int lane = threadIdx.x & 15;
    if (node >= n) return;
    int s0 = row_ptr[node];
    int s1 = row_ptr[node + 1];
    float acc[8] = {0.f, 0.f, 0.f, 0.f, 0.f, 0.f, 0.f, 0.f};
    int e = s0;
    for (; e + 4 <= s1; e += 4) {
        int i0 = csr_src[e];
        int i1 = csr_src[e + 1];
        int i2 = csr_src[e + 2];
        int i3 = csr_src[e + 3];
        u16x8 v0 = *(const u16x8*)&h[(size_t)i0 * D + lane * 8];
        u16x8 v1 = *(const u16x8*)&h[(size_t)i1 * D + lane * 8];
        u16x8 v2 = *(const u16x8*)&h[(size_t)i2 * D + lane * 8];
        u16x8 v3 = *(const u16x8*)&h[(size_t)i3 * D + lane * 8];
        #pragma unroll
        for (int i = 0; i < 8; ++i)
            acc[i] += bf2f(v0[i]) + bf2f(v1[i]) + bf2f(v2[i]) + bf2f(v3[i]);
    }
    for (; e < s1; ++e) {
        int src = csr_src[e];
        u16x8 v = *(const u16x8*)&h[(size_t)src * D + lane * 8];
        #pragma unroll
        for (int i = 0; i < 8; ++i) acc[i] += bf2f(v[i]);
    }
    int dg = s1 - s0;
    float sc = (dg > 0) ? (1.0f / (float)dg) : 0.0f;
    u16x8 o;
    #pragma unroll
    for (int i = 0; i < 8; ++i) o[i] = f2bf(acc[i] * sc);
    *(u16x8*)&agg[(size_t)node * D + lane * 8] = o;
}

// ---------------- fused SAGE layer: MFMA GEMM + bias + LN + SiLU ----------------
__global__ __launch_bounds__(256) void sage_mfma(
    const ushort_t* __restrict__ agg, const ushort_t* __restrict__ hin,
    const ushort_t* __restrict__ Wl, const ushort_t* __restrict__ Wr,
    const float* __restrict__ bl, const float* __restrict__ br,
    const float* __restrict__ lng, const float* __restrict__ lnb,
    ushort_t* __restrict__ hout, int n) {
    __shared__ ushort_t tile[64][132];

    const int tid = threadIdx.x;
    const int wave = tid >> 6;
    const int lane = tid & 63;
    const int quad = lane >> 4;
    const int l16 = lane & 15;
    const int n0w = blockIdx.x * 64 + wave * 16;

    int arow = n0w + l16;
    if (arow >= n) arow = n - 1;

    f32x4 acc[8];
    #pragma unroll
    for (int jt = 0; jt < 8; ++jt) acc[jt] = (f32x4){0.f, 0.f, 0.f, 0.f};

    #pragma unroll
    for (int c = 0; c < 8; ++c) {
        const ushort_t* __restrict__ act = (c < 4) ? agg : hin;
        const ushort_t* __restrict__ W = (c < 4) ? Wl : Wr;
        const int kb = (c & 3) * 32;
        bf16x8 afrag = *(const bf16x8*)&act[(size_t)arow * D + kb + quad * 8];
        #pragma unroll
        for (int jt = 0; jt < 8; ++jt) {
            bf16x8 bfrag = *(const bf16x8*)&W[(size_t)(jt * 16 + l16) * D + kb + quad * 8];
            acc[jt] = __builtin_amdgcn_mfma_f32_16x16x32_bf16(afrag, bfrag, acc[jt], 0, 0, 0);
        }
    }

    float bsum[8], g[8], bb[8];
    #pragma unroll
    for (int jt = 0; jt < 8; ++jt) {
        int j = jt * 16 + l16;
        bsum[jt] = bl[j] + br[j];
        g[jt] = lng[j];
        bb[jt] = lnb[j];
    }
    #pragma unroll
    for (int r = 0; r < 4; ++r) {
        float v[8];
        float s = 0.f, s2 = 0.f;
        #pragma unroll
        for (int jt = 0; jt < 8; ++jt) {
            float t = acc[jt][r] + bsum[jt];
            v[jt] = t;
            s += t; s2 += t * t;
        }
        #pragma unroll
        for (int off = 1; off < 16; off <<= 1) {
            s += __shfl_xor(s, off, 64);
            s2 += __shfl_xor(s2, off, 64);
        }
        float mean = s * (1.0f / 128.0f);
        float var = s2 * (1.0f / 128.0f) - mean * mean;
        float rstd = rsqrtf(var + LN_EPS);
        int rowb = wave * 16 + quad * 4 + r;
        #pragma unroll
        for (int jt = 0; jt < 8; ++jt) {
            float z = (v[jt] - mean) * rstd * g[jt] + bb[jt];
            float sv = z / (1.0f + expf(-z));
            tile[rowb][jt * 16 + l16] = f2bf(sv);
        }
    }
    __syncthreads();
    int row = tid >> 2, seg = tid & 3;
    int node = blockIdx.x * 64 + row;
    if (node < n) {
        #pragma unroll
        for (int k2 = 0; k2 < 4; ++k2) {
            u16x8 vv = *(const u16x8*)&tile[row][seg * 32 + k2 * 8];
            *(u16x8*)&hout[(size_t)node * D + seg * 32 + k2 * 8] = vv;
        }
    }
}

// ---------------- fused MLP head: MFMA GEMM + bias + ReLU + dot(w2) + b2 ----------------
__global__ __launch_bounds__(256) void mlp_head_mfma(
    const ushort_t* __restrict__ hin, const ushort_t* __restrict__ W1,
    const float* __restrict__ b1, const float* __restrict__ w2,
    const float* __restrict__ b2, float* __restrict__ out, int n) {
    const int tid = threadIdx.x;
    const int wave = tid >> 6;
    const int lane = tid & 63;
    const int quad = lane >> 4;
    const int l16 = lane & 15;
    const int n0w = blockIdx.x * 64 + wave * 16;

    int arow = n0w + l16;
    if (arow >= n) arow = n - 1;

    f32x4 acc[8];
    #pragma unroll
    for (int jt = 0; jt < 8; ++jt) acc[jt] = (f32x4){0.f, 0.f, 0.f, 0.f};

    #pragma unroll
    for (int c = 0; c < 4; ++c) {
        const int kb = c * 32;
        bf16x8 afrag = *(const bf16x8*)&hin[(size_t)arow * D + kb + quad * 8];
        #pragma unroll
        for (int jt = 0; jt < 8; ++jt) {
            bf16x8 bfrag = *(const bf16x8*)&W1[(size_t)(jt * 16 + l16) * D + kb + quad * 8];
            acc[jt] = __builtin_amdgcn_mfma_f32_16x16x32_bf16(afrag, bfrag, acc[jt], 0, 0, 0);
        }
    }

    float bias1[8], wv2[8];
    #pragma unroll
    for (int jt = 0; jt < 8; ++jt) {
        int j = jt * 16 + l16;
        bias1[jt] = b1[j];
        wv2[jt] = w2[j];
    }
    float b2v = b2[0];
    #pragma unroll
    for (int r = 0; r < 4; ++r) {
        float p = 0.f;
        #pragma unroll
        for (int jt = 0; jt < 8; ++jt) {
            float v = acc[jt][r] + bias1[jt];
            v = fmaxf(v, 0.0f);
            p += v * wv2[jt];
        }
        #pragma unroll
        for (int off = 1; off < 16; off <<= 1) p += __shfl_xor(p, off, 64);
        if (l16 == 0) {
            int node = n0w + quad * 4 + r;
            if (node < n) out[node] = p + b2v;
        }
    }
}

// ---------------- launch ----------------
static inline size_t align_up(size_t v, size_t a) { return (v + a - 1) & ~(a - 1); }

extern "C" void kernel_launch(void* const* d_in, const int* in_sizes, int n_in,
                              void* d_out, int out_size, void* d_ws, size_t ws_size,
                              hipStream_t stream) {
    const float* x       = (const float*)d_in[0];
    const int*   ei      = (const int*)d_in[1];
    const float* lin_l_w = (const float*)d_in[2];
    const float* lin_l_b = (const float*)d_in[3];
    const float* lin_r_w = (const float*)d_in[4];
    const float* lin_r_b = (const float*)d_in[5];
    const float* ln_g    = (const float*)d_in[6];
    const float* ln_b    = (const float*)d_in[7];
    const float* mlp_w1  = (const float*)d_in[8];
    const float* mlp_b1  = (const float*)d_in[9];
    const float* mlp_w2  = (const float*)d_in[10];
    const float* mlp_b2  = (const float*)d_in[11];
    float* out = (float*)d_out;

    const int N = in_sizes[0] / D;   // 100000
    const int E = in_sizes[1] / 2;   // 1600000

    // workspace layout
    char* w = (char*)d_ws;
    size_t off = 0;
    int* deg = (int*)(w + off);        off = align_up(off + sizeof(int) * (size_t)N, 512);
    int* row_ptr = (int*)(w + off);    off = align_up(off + sizeof(int) * (size_t)(N + 1), 512);
    int* cursor = (int*)(w + off);     off = align_up(off + sizeof(int) * (size_t)N, 512);
    int* blk_sums = (int*)(w + off);   off = align_up(off + sizeof(int) * 1024, 512);
    int* csr_src = (int*)(w + off);    off = align_up(off + sizeof(int) * (size_t)E, 512);
    ushort_t* x_bf = (ushort_t*)(w + off);   off = align_up(off + 2ull * N * D, 512);
    ushort_t* h1_bf = (ushort_t*)(w + off);  off = align_up(off + 2ull * N * D, 512);
    ushort_t* h2_bf = (ushort_t*)(w + off);  off = align_up(off + 2ull * N * D, 512);
    ushort_t* agg_bf = (ushort_t*)(w + off); off = align_up(off + 2ull * N * D, 512);
    ushort_t* wl_bf = (ushort_t*)(w + off);  off = align_up(off + 2ull * 2 * D * D, 512);
    ushort_t* wr_bf = (ushort_t*)(w + off);  off = align_up(off + 2ull * 2 * D * D, 512);
    ushort_t* w1_bf = (ushort_t*)(w + off);  off = align_up(off + 2ull * D * D, 512);

    hipMemsetAsync(deg, 0, sizeof(int) * (size_t)N, stream);
    hipMemsetAsync(cursor, 0, sizeof(int) * (size_t)N, stream);

    // weight + input casts (bf16)
    cast_f32_bf16<<<(2 * D * D) / (8 * 256), 256, 0, stream>>>(lin_l_w, wl_bf, 2 * D * D);
    cast_f32_bf16<<<(2 * D * D) / (8 * 256), 256, 0, stream>>>(lin_r_w, wr_bf, 2 * D * D);
    cast_f32_bf16<<<(D * D + 8 * 256 - 1) / (8 * 256), 256, 0, stream>>>(mlp_w1, w1_bf, D * D);
    cast_f32_bf16<<<(N * D) / (8 * 256), 256, 0, stream>>>(x, x_bf, N * D);

    // graph build
    degree_kernel<<<(E + 255) / 256, 256, 0, stream>>>(ei, E, deg);
    const int nb = (N + SCAN_CHUNK - 1) / SCAN_CHUNK;   // 49 for N=100000
    block_sum_kernel<<<nb, SCAN_BLOCK, 0, stream>>>(deg, blk_sums, N);
    scan_sums_kernel<<<1, 1024, 0, stream>>>(blk_sums, nb, row_ptr, N);
    scan_chunk_kernel<<<nb, SCAN_BLOCK, 0, stream>>>(deg, blk_sums, row_ptr, N);
    fill_csr_kernel<<<(E + 255) / 256, 256, 0, stream>>>(ei, E, row_ptr, cursor, csr_src);

    const int gemm_grid = (N + 63) / 64;
    const int agg_grid = (N + 15) / 16;

    // layer 0
    aggregate_bf16<<<agg_grid, 256, 0, stream>>>(x_bf, row_ptr, csr_src, agg_bf, N);
    sage_mfma<<<gemm_grid, 256, 0, stream>>>(
        agg_bf, x_bf, wl_bf, wr_bf, lin_l_b, lin_r_b, ln_g, ln_b, h1_bf, N);
    // layer 1
    aggregate_bf16<<<agg_grid, 256, 0, stream>>>(h1_bf, row_ptr, csr_src, agg_bf, N);
    sage_mfma<<<gemm_grid, 256, 0, stream>>>(
        agg_bf, h1_bf, wl_bf + D * D, wr_bf + D * D, lin_l_b + D, lin_r_b + D,
        ln_g + D, ln_b + D, h2_bf, N);
    // head
    mlp_head_mfma<<<gemm_grid, 256, 0, stream>>>(h2_bf, w1_bf, mlp_b1, mlp_w2, mlp_b2, out, N);
}

// Round 4
// 536.695 us; speedup vs baseline: 2.0638x; 1.0732x over previous
//
#include <hip/hip_runtime.h>
#include <math.h>

#define D 128
#define LN_EPS 1e-5f

#define SCAN_ITEMS 8
#define SCAN_BLOCK 256
#define SCAN_CHUNK (SCAN_ITEMS * SCAN_BLOCK)   // 2048 elements per block

#define NB_SHIFT 7                   // 128 nodes per bucket
#define BIN_EPT 16                   // edges per thread in bin pass
#define BIN_CHUNK (BIN_EPT * 256)    // 4096 edges per block

typedef unsigned short ushort_t;
typedef unsigned int uint_t;
typedef __attribute__((ext_vector_type(8))) short bf16x8;
typedef __attribute__((ext_vector_type(8))) unsigned short u16x8;
typedef __attribute__((ext_vector_type(4))) float f32x4;

static __device__ __forceinline__ float bf2f(ushort_t u) {
    union { uint_t i; float f; } c; c.i = ((uint_t)u) << 16; return c.f;
}
static __device__ __forceinline__ ushort_t f2bf(float f) {
    union { float f; uint_t i; } c; c.f = f;
    uint_t u = c.i;
    uint_t r = (u + 0x7fffu + ((u >> 16) & 1u)) >> 16;   // RNE
    return (ushort_t)r;
}

// ---------------- casts ----------------
__global__ __launch_bounds__(256) void cast_f32_bf16(const float* __restrict__ in,
                                                     ushort_t* __restrict__ out, int n) {
    int i = (blockIdx.x * 256 + threadIdx.x) * 8;
    if (i + 8 > n) return;
    float4 a = *(const float4*)&in[i];
    float4 b = *(const float4*)&in[i + 4];
    u16x8 v;
    v[0] = f2bf(a.x); v[1] = f2bf(a.y); v[2] = f2bf(a.z); v[3] = f2bf(a.w);
    v[4] = f2bf(b.x); v[5] = f2bf(b.y); v[6] = f2bf(b.z); v[7] = f2bf(b.w);
    *(u16x8*)&out[i] = v;
}

// ---------------- graph build ----------------
__global__ __launch_bounds__(256) void degree_kernel(const int* __restrict__ ei, int E,
                                                     int* __restrict__ deg) {
    int e = blockIdx.x * 256 + threadIdx.x;
    if (e >= E) return;
    atomicAdd(&deg[ei[E + e]], 1);
}

// hierarchical exclusive scan: pass 1 — per-block sums
__global__ __launch_bounds__(SCAN_BLOCK) void block_sum_kernel(const int* __restrict__ deg,
                                                               int* __restrict__ blk_sums, int n) {
    int base = blockIdx.x * SCAN_CHUNK + threadIdx.x * SCAN_ITEMS;
    int s = 0;
    #pragma unroll
    for (int i = 0; i < SCAN_ITEMS; ++i) {
        int idx = base + i;
        if (idx < n) s += deg[idx];
    }
    #pragma unroll
    for (int off = 1; off < 64; off <<= 1) s += __shfl_xor(s, off, 64);
    __shared__ int ws[4];
    if ((threadIdx.x & 63) == 0) ws[threadIdx.x >> 6] = s;
    __syncthreads();
    if (threadIdx.x == 0) blk_sums[blockIdx.x] = ws[0] + ws[1] + ws[2] + ws[3];
}

// pass 2 — single-block exclusive scan of block sums (nb <= 1024); writes row_ptr[n]=total
__global__ __launch_bounds__(1024) void scan_sums_kernel(int* __restrict__ blk_sums, int nb,
                                                         int* __restrict__ row_ptr, int n) {
    __shared__ int wt[16];
    int i = threadIdx.x;
    int v = (i < nb) ? blk_sums[i] : 0;
    int lane = i & 63, wid = i >> 6;
    int incl = v;
    #pragma unroll
    for (int off = 1; off < 64; off <<= 1) {
        int t = __shfl_up(incl, off, 64);
        if (lane >= off) incl += t;
    }
    if (lane == 63) wt[wid] = incl;
    __syncthreads();
    int prefix = 0;
    for (int w = 0; w < wid; ++w) prefix += wt[w];
    if (i < nb) blk_sums[i] = prefix + incl - v;   // exclusive block offsets, in place
    if (i == 0) {
        int tot = 0;
        for (int w = 0; w < 16; ++w) tot += wt[w];
        row_ptr[n] = tot;
    }
}

// pass 3 — per-block local exclusive scan + block offset
__global__ __launch_bounds__(SCAN_BLOCK) void scan_chunk_kernel(const int* __restrict__ deg,
                                                                const int* __restrict__ blk_offs,
                                                                int* __restrict__ row_ptr, int n) {
    int base = blockIdx.x * SCAN_CHUNK + threadIdx.x * SCAN_ITEMS;
    int vals[SCAN_ITEMS];
    int s = 0;
    #pragma unroll
    for (int i = 0; i < SCAN_ITEMS; ++i) {
        int idx = base + i;
        int v = (idx < n) ? deg[idx] : 0;
        vals[i] = s;
        s += v;
    }
    int lane = threadIdx.x & 63, wid = threadIdx.x >> 6;
    int incl = s;
    #pragma unroll
    for (int off = 1; off < 64; off <<= 1) {
        int t = __shfl_up(incl, off, 64);
        if (lane >= off) incl += t;
    }
    __shared__ int wt[4];
    if (lane == 63) wt[wid] = incl;
    __syncthreads();
    int prefix = 0;
    for (int w = 0; w < wid; ++w) prefix += wt[w];
    int texcl = prefix + incl - s + blk_offs[blockIdx.x];
    #pragma unroll
    for (int i = 0; i < SCAN_ITEMS; ++i) {
        int idx = base + i;
        if (idx < n) row_ptr[idx] = texcl + vals[i];
    }
}

// bucket cursors: bcur[b] = row_ptr[min(b<<NB_SHIFT, n)]
__global__ __launch_bounds__(1024) void init_bcur_kernel(const int* __restrict__ row_ptr,
                                                         int* __restrict__ bcur, int nb, int n) {
    int b = threadIdx.x;
    if (b < nb) {
        int node = b << NB_SHIFT;
        if (node > n) node = n;
        bcur[b] = row_ptr[node];
    }
}

// bin pass: scatter (src,dst) pairs into per-bucket regions (CSR coordinate space).
// Per-block LDS histogram -> one global reservation per bucket -> locality-friendly writes.
__global__ __launch_bounds__(256) void bin_edges_kernel(const int* __restrict__ ei, int E,
                                                        int* __restrict__ bcur,
                                                        int2* __restrict__ pairs, int nb) {
    __shared__ int hist[1024];
    __shared__ int base[1024];
    const int tid = threadIdx.x;
    for (int i = tid; i < nb; i += 256) hist[i] = 0;
    __syncthreads();

    int e0 = blockIdx.x * BIN_CHUNK;
    int s_r[BIN_EPT], d_r[BIN_EPT], idx_r[BIN_EPT];
    #pragma unroll
    for (int i = 0; i < BIN_EPT; ++i) {
        int e = e0 + i * 256 + tid;
        if (e < E) {
            s_r[i] = ei[e];
            d_r[i] = ei[E + e];
            idx_r[i] = atomicAdd(&hist[d_r[i] >> NB_SHIFT], 1);
        }
    }
    __syncthreads();
    for (int i = tid; i < nb; i += 256) {
        int c = hist[i];
        base[i] = c ? atomicAdd(&bcur[i], c) : 0;
    }
    __syncthreads();
    #pragma unroll
    for (int i = 0; i < BIN_EPT; ++i) {
        int e = e0 + i * 256 + tid;
        if (e < E) {
            int pos = base[d_r[i] >> NB_SHIFT] + idx_r[i];
            pairs[pos] = make_int2(s_r[i], d_r[i]);
        }
    }
}

// final CSR fill from binned pairs: cursor atomics + writes stay in a ~12 KB window.
__global__ __launch_bounds__(256) void csr_fill_binned(const int2* __restrict__ pairs, int E,
                                                       const int* __restrict__ row_ptr,
                                                       int* __restrict__ cursor,
                                                       int* __restrict__ csr_src) {
    int e = blockIdx.x * 256 + threadIdx.x;
    if (e >= E) return;
    int2 p = pairs[e];
    int pos = row_ptr[p.y] + atomicAdd(&cursor[p.y], 1);
    csr_src[pos] = p.x;
}

// ---------------- aggregation (bf16 gather, fp32 accum, bf16 out) ----------------
__global__ __launch_bounds__(256) void aggregate_bf16(const ushort_t* __restrict__ h,
                                                      const int* __restrict__ row_ptr,
                                                      const int* __restrict__ csr_src,
                                                      ushort_t* __restrict__ agg, int n) {
    int node = blockIdx.x * 16 + (threadIdx.x >> 4);
    int lane = threadIdx.x & 15;
    if (node >= n) return;
    int s0 = row_ptr[node];
    int s1 = row_ptr[node + 1];
    float acc[8] = {0.f, 0.f, 0.f, 0.f, 0.f, 0.f, 0.f, 0.f};
    int e = s0;
    for (; e + 4 <= s1; e += 4) {
        int i0 = csr_src[e];
        int i1 = csr_src[e + 1];
        int i2 = csr_src[e + 2];
        int i3 = csr_src[e + 3];
        u16x8 v0 = *(const u16x8*)&h[(size_t)i0 * D + lane * 8];
        u16x8 v1 = *(const u16x8*)&h[(size_t)i1 * D + lane * 8];
        u16x8 v2 = *(const u16x8*)&h[(size_t)i2 * D + lane * 8];
        u16x8 v3 = *(const u16x8*)&h[(size_t)i3 * D + lane * 8];
        #pragma unroll
        for (int i = 0; i < 8; ++i)
            acc[i] += bf2f(v0[i]) + bf2f(v1[i]) + bf2f(v2[i]) + bf2f(v3[i]);
    }
    for (; e < s1; ++e) {
        int src = csr_src[e];
        u16x8 v = *(const u16x8*)&h[(size_t)src * D + lane * 8];
        #pragma unroll
        for (int i = 0; i < 8; ++i) acc[i] += bf2f(v[i]);
    }
    int dg = s1 - s0;
    float sc = (dg > 0) ? (1.0f / (float)dg) : 0.0f;
    u16x8 o;
    #pragma unroll
    for (int i = 0; i < 8; ++i) o[i] = f2bf(acc[i] * sc);
    *(u16x8*)&agg[(size_t)node * D + lane * 8] = o;
}

// ---------------- fused SAGE layer: MFMA GEMM + bias + LN + SiLU ----------------
__global__ __launch_bounds__(256) void sage_mfma(
    const ushort_t* __restrict__ agg, const ushort_t* __restrict__ hin,
    const ushort_t* __restrict__ Wl, const ushort_t* __restrict__ Wr,
    const float* __restrict__ bl, const float* __restrict__ br,
    const float* __restrict__ lng, const float* __restrict__ lnb,
    ushort_t* __restrict__ hout, int n) {
    __shared__ ushort_t tile[64][132];

    const int tid = threadIdx.x;
    const int wave = tid >> 6;
    const int lane = tid & 63;
    const int quad = lane >> 4;
    const int l16 = lane & 15;
    const int n0w = blockIdx.x * 64 + wave * 16;

    int arow = n0w + l16;
    if (arow >= n) arow = n - 1;

    f32x4 acc[8];
    #pragma unroll
    for (int jt = 0; jt < 8; ++jt) acc[jt] = (f32x4){0.f, 0.f, 0.f, 0.f};

    #pragma unroll
    for (int c = 0; c < 8; ++c) {
        const ushort_t* __restrict__ act = (c < 4) ? agg : hin;
        const ushort_t* __restrict__ W = (c < 4) ? Wl : Wr;
        const int kb = (c & 3) * 32;
        bf16x8 afrag = *(const bf16x8*)&act[(size_t)arow * D + kb + quad * 8];
        #pragma unroll
        for (int jt = 0; jt < 8; ++jt) {
            bf16x8 bfrag = *(const bf16x8*)&W[(size_t)(jt * 16 + l16) * D + kb + quad * 8];
            acc[jt] = __builtin_amdgcn_mfma_f32_16x16x32_bf16(afrag, bfrag, acc[jt], 0, 0, 0);
        }
    }

    float bsum[8], g[8], bb[8];
    #pragma unroll
    for (int jt = 0; jt < 8; ++jt) {
        int j = jt * 16 + l16;
        bsum[jt] = bl[j] + br[j];
        g[jt] = lng[j];
        bb[jt] = lnb[j];
    }
    #pragma unroll
    for (int r = 0; r < 4; ++r) {
        float v[8];
        float s = 0.f, s2 = 0.f;
        #pragma unroll
        for (int jt = 0; jt < 8; ++jt) {
            float t = acc[jt][r] + bsum[jt];
            v[jt] = t;
            s += t; s2 += t * t;
        }
        #pragma unroll
        for (int off = 1; off < 16; off <<= 1) {
            s += __shfl_xor(s, off, 64);
            s2 += __shfl_xor(s2, off, 64);
        }
        float mean = s * (1.0f / 128.0f);
        float var = s2 * (1.0f / 128.0f) - mean * mean;
        float rstd = rsqrtf(var + LN_EPS);
        int rowb = wave * 16 + quad * 4 + r;
        #pragma unroll
        for (int jt = 0; jt < 8; ++jt) {
            float z = (v[jt] - mean) * rstd * g[jt] + bb[jt];
            float sv = z / (1.0f + expf(-z));
            tile[rowb][jt * 16 + l16] = f2bf(sv);
        }
    }
    __syncthreads();
    int row = tid >> 2, seg = tid & 3;
    int node = blockIdx.x * 64 + row;
    if (node < n) {
        #pragma unroll
        for (int k2 = 0; k2 < 4; ++k2) {
            u16x8 vv = *(const u16x8*)&tile[row][seg * 32 + k2 * 8];
            *(u16x8*)&hout[(size_t)node * D + seg * 32 + k2 * 8] = vv;
        }
    }
}

// ---------------- fused MLP head: MFMA GEMM + bias + ReLU + dot(w2) + b2 ----------------
__global__ __launch_bounds__(256) void mlp_head_mfma(
    const ushort_t* __restrict__ hin, const ushort_t* __restrict__ W1,
    const float* __restrict__ b1, const float* __restrict__ w2,
    const float* __restrict__ b2, float* __restrict__ out, int n) {
    const int tid = threadIdx.x;
    const int wave = tid >> 6;
    const int lane = tid & 63;
    const int quad = lane >> 4;
    const int l16 = lane & 15;
    const int n0w = blockIdx.x * 64 + wave * 16;

    int arow = n0w + l16;
    if (arow >= n) arow = n - 1;

    f32x4 acc[8];
    #pragma unroll
    for (int jt = 0; jt < 8; ++jt) acc[jt] = (f32x4){0.f, 0.f, 0.f, 0.f};

    #pragma unroll
    for (int c = 0; c < 4; ++c) {
        const int kb = c * 32;
        bf16x8 afrag = *(const bf16x8*)&hin[(size_t)arow * D + kb + quad * 8];
        #pragma unroll
        for (int jt = 0; jt < 8; ++jt) {
            bf16x8 bfrag = *(const bf16x8*)&W1[(size_t)(jt * 16 + l16) * D + kb + quad * 8];
            acc[jt] = __builtin_amdgcn_mfma_f32_16x16x32_bf16(afrag, bfrag, acc[jt], 0, 0, 0);
        }
    }

    float bias1[8], wv2[8];
    #pragma unroll
    for (int jt = 0; jt < 8; ++jt) {
        int j = jt * 16 + l16;
        bias1[jt] = b1[j];
        wv2[jt] = w2[j];
    }
    float b2v = b2[0];
    #pragma unroll
    for (int r = 0; r < 4; ++r) {
        float p = 0.f;
        #pragma unroll
        for (int jt = 0; jt < 8; ++jt) {
            float v = acc[jt][r] + bias1[jt];
            v = fmaxf(v, 0.0f);
            p += v * wv2[jt];
        }
        #pragma unroll
        for (int off = 1; off < 16; off <<= 1) p += __shfl_xor(p, off, 64);
        if (l16 == 0) {
            int node = n0w + quad * 4 + r;
            if (node < n) out[node] = p + b2v;
        }
    }
}

// ---------------- launch ----------------
static inline size_t align_up(size_t v, size_t a) { return (v + a - 1) & ~(a - 1); }

extern "C" void kernel_launch(void* const* d_in, const int* in_sizes, int n_in,
                              void* d_out, int out_size, void* d_ws, size_t ws_size,
                              hipStream_t stream) {
    const float* x       = (const float*)d_in[0];
    const int*   ei      = (const int*)d_in[1];
    const float* lin_l_w = (const float*)d_in[2];
    const float* lin_l_b = (const float*)d_in[3];
    const float* lin_r_w = (const float*)d_in[4];
    const float* lin_r_b = (const float*)d_in[5];
    const float* ln_g    = (const float*)d_in[6];
    const float* ln_b    = (const float*)d_in[7];
    const float* mlp_w1  = (const float*)d_in[8];
    const float* mlp_b1  = (const float*)d_in[9];
    const float* mlp_w2  = (const float*)d_in[10];
    const float* mlp_b2  = (const float*)d_in[11];
    float* out = (float*)d_out;

    const int N = in_sizes[0] / D;   // 100000
    const int E = in_sizes[1] / 2;   // 1600000
    const int NB = (N + (1 << NB_SHIFT) - 1) >> NB_SHIFT;   // 782

    // workspace layout
    char* w = (char*)d_ws;
    size_t off = 0;
    int* deg = (int*)(w + off);        off = align_up(off + sizeof(int) * (size_t)N, 512);
    int* row_ptr = (int*)(w + off);    off = align_up(off + sizeof(int) * (size_t)(N + 1), 512);
    int* cursor = (int*)(w + off);     off = align_up(off + sizeof(int) * (size_t)N, 512);
    int* blk_sums = (int*)(w + off);   off = align_up(off + sizeof(int) * 1024, 512);
    int* bcur = (int*)(w + off);       off = align_up(off + sizeof(int) * 1024, 512);
    int* csr_src = (int*)(w + off);    off = align_up(off + sizeof(int) * (size_t)E, 512);
    int2* pairs = (int2*)(w + off);    off = align_up(off + sizeof(int2) * (size_t)E, 512);
    ushort_t* x_bf = (ushort_t*)(w + off);   off = align_up(off + 2ull * N * D, 512);
    ushort_t* h1_bf = (ushort_t*)(w + off);  off = align_up(off + 2ull * N * D, 512);
    ushort_t* h2_bf = (ushort_t*)(w + off);  off = align_up(off + 2ull * N * D, 512);
    ushort_t* agg_bf = (ushort_t*)(w + off); off = align_up(off + 2ull * N * D, 512);
    ushort_t* wl_bf = (ushort_t*)(w + off);  off = align_up(off + 2ull * 2 * D * D, 512);
    ushort_t* wr_bf = (ushort_t*)(w + off);  off = align_up(off + 2ull * 2 * D * D, 512);
    ushort_t* w1_bf = (ushort_t*)(w + off);  off = align_up(off + 2ull * D * D, 512);

    hipMemsetAsync(deg, 0, sizeof(int) * (size_t)N, stream);
    hipMemsetAsync(cursor, 0, sizeof(int) * (size_t)N, stream);

    // weight + input casts (bf16)
    cast_f32_bf16<<<(2 * D * D) / (8 * 256), 256, 0, stream>>>(lin_l_w, wl_bf, 2 * D * D);
    cast_f32_bf16<<<(2 * D * D) / (8 * 256), 256, 0, stream>>>(lin_r_w, wr_bf, 2 * D * D);
    cast_f32_bf16<<<(D * D + 8 * 256 - 1) / (8 * 256), 256, 0, stream>>>(mlp_w1, w1_bf, D * D);
    cast_f32_bf16<<<(N * D) / (8 * 256), 256, 0, stream>>>(x, x_bf, N * D);

    // graph build
    degree_kernel<<<(E + 255) / 256, 256, 0, stream>>>(ei, E, deg);
    const int nb_scan = (N + SCAN_CHUNK - 1) / SCAN_CHUNK;
    block_sum_kernel<<<nb_scan, SCAN_BLOCK, 0, stream>>>(deg, blk_sums, N);
    scan_sums_kernel<<<1, 1024, 0, stream>>>(blk_sums, nb_scan, row_ptr, N);
    scan_chunk_kernel<<<nb_scan, SCAN_BLOCK, 0, stream>>>(deg, blk_sums, row_ptr, N);
    init_bcur_kernel<<<1, 1024, 0, stream>>>(row_ptr, bcur, NB, N);
    bin_edges_kernel<<<(E + BIN_CHUNK - 1) / BIN_CHUNK, 256, 0, stream>>>(ei, E, bcur, pairs, NB);
    csr_fill_binned<<<(E + 255) / 256, 256, 0, stream>>>(pairs, E, row_ptr, cursor, csr_src);

    const int gemm_grid = (N + 63) / 64;
    const int agg_grid = (N + 15) / 16;

    // layer 0
    aggregate_bf16<<<agg_grid, 256, 0, stream>>>(x_bf, row_ptr, csr_src, agg_bf, N);
    sage_mfma<<<gemm_grid, 256, 0, stream>>>(
        agg_bf, x_bf, wl_bf, wr_bf, lin_l_b, lin_r_b, ln_g, ln_b, h1_bf, N);
    // layer 1
    aggregate_bf16<<<agg_grid, 256, 0, stream>>>(h1_bf, row_ptr, csr_src, agg_bf, N);
    sage_mfma<<<gemm_grid, 256, 0, stream>>>(
        agg_bf, h1_bf, wl_bf + D * D, wr_bf + D * D, lin_l_b + D, lin_r_b + D,
        ln_g + D, ln_b + D, h2_bf, N);
    // head
    mlp_head_mfma<<<gemm_grid, 256, 0, stream>>>(h2_bf, w1_bf, mlp_b1, mlp_w2, mlp_b2, out, N);
}

// Round 5
// 501.582 us; speedup vs baseline: 2.2082x; 1.0700x over previous
//
#include <hip/hip_runtime.h>
#include <math.h>

#define D 128
#define LN_EPS 1e-5f

#define SCAN_ITEMS 8
#define SCAN_BLOCK 256
#define SCAN_CHUNK (SCAN_ITEMS * SCAN_BLOCK)   // 2048 elements per block

#define NB_SHIFT 7                   // 128 nodes per bucket
#define BIN_EPT 16                   // edges per thread in bin pass
#define BIN_CHUNK (BIN_EPT * 256)    // 4096 edges per block

typedef unsigned short ushort_t;
typedef unsigned int uint_t;
typedef __attribute__((ext_vector_type(8))) short bf16x8;
typedef __attribute__((ext_vector_type(8))) unsigned short u16x8;
typedef __attribute__((ext_vector_type(4))) float f32x4;

static __device__ __forceinline__ float bf2f(ushort_t u) {
    union { uint_t i; float f; } c; c.i = ((uint_t)u) << 16; return c.f;
}
static __device__ __forceinline__ ushort_t f2bf(float f) {
    union { float f; uint_t i; } c; c.f = f;
    uint_t u = c.i;
    uint_t r = (u + 0x7fffu + ((u >> 16) & 1u)) >> 16;   // RNE
    return (ushort_t)r;
}

// ---------------- casts ----------------
__global__ __launch_bounds__(256) void cast_f32_bf16(const float* __restrict__ in,
                                                     ushort_t* __restrict__ out, int n) {
    int i = (blockIdx.x * 256 + threadIdx.x) * 8;
    if (i + 8 > n) return;
    float4 a = *(const float4*)&in[i];
    float4 b = *(const float4*)&in[i + 4];
    u16x8 v;
    v[0] = f2bf(a.x); v[1] = f2bf(a.y); v[2] = f2bf(a.z); v[3] = f2bf(a.w);
    v[4] = f2bf(b.x); v[5] = f2bf(b.y); v[6] = f2bf(b.z); v[7] = f2bf(b.w);
    *(u16x8*)&out[i] = v;
}

// ---------------- graph build ----------------
__global__ __launch_bounds__(256) void degree_kernel(const int* __restrict__ ei, int E,
                                                     int* __restrict__ deg) {
    int e = blockIdx.x * 256 + threadIdx.x;
    if (e >= E) return;
    atomicAdd(&deg[ei[E + e]], 1);
}

__global__ __launch_bounds__(SCAN_BLOCK) void block_sum_kernel(const int* __restrict__ deg,
                                                               int* __restrict__ blk_sums, int n) {
    int base = blockIdx.x * SCAN_CHUNK + threadIdx.x * SCAN_ITEMS;
    int s = 0;
    #pragma unroll
    for (int i = 0; i < SCAN_ITEMS; ++i) {
        int idx = base + i;
        if (idx < n) s += deg[idx];
    }
    #pragma unroll
    for (int off = 1; off < 64; off <<= 1) s += __shfl_xor(s, off, 64);
    __shared__ int ws[4];
    if ((threadIdx.x & 63) == 0) ws[threadIdx.x >> 6] = s;
    __syncthreads();
    if (threadIdx.x == 0) blk_sums[blockIdx.x] = ws[0] + ws[1] + ws[2] + ws[3];
}

__global__ __launch_bounds__(1024) void scan_sums_kernel(int* __restrict__ blk_sums, int nb,
                                                         int* __restrict__ row_ptr, int n) {
    __shared__ int wt[16];
    int i = threadIdx.x;
    int v = (i < nb) ? blk_sums[i] : 0;
    int lane = i & 63, wid = i >> 6;
    int incl = v;
    #pragma unroll
    for (int off = 1; off < 64; off <<= 1) {
        int t = __shfl_up(incl, off, 64);
        if (lane >= off) incl += t;
    }
    if (lane == 63) wt[wid] = incl;
    __syncthreads();
    int prefix = 0;
    for (int w = 0; w < wid; ++w) prefix += wt[w];
    if (i < nb) blk_sums[i] = prefix + incl - v;
    if (i == 0) {
        int tot = 0;
        for (int w = 0; w < 16; ++w) tot += wt[w];
        row_ptr[n] = tot;
    }
}

__global__ __launch_bounds__(SCAN_BLOCK) void scan_chunk_kernel(const int* __restrict__ deg,
                                                                const int* __restrict__ blk_offs,
                                                                int* __restrict__ row_ptr, int n) {
    int base = blockIdx.x * SCAN_CHUNK + threadIdx.x * SCAN_ITEMS;
    int vals[SCAN_ITEMS];
    int s = 0;
    #pragma unroll
    for (int i = 0; i < SCAN_ITEMS; ++i) {
        int idx = base + i;
        int v = (idx < n) ? deg[idx] : 0;
        vals[i] = s;
        s += v;
    }
    int lane = threadIdx.x & 63, wid = threadIdx.x >> 6;
    int incl = s;
    #pragma unroll
    for (int off = 1; off < 64; off <<= 1) {
        int t = __shfl_up(incl, off, 64);
        if (lane >= off) incl += t;
    }
    __shared__ int wt[4];
    if (lane == 63) wt[wid] = incl;
    __syncthreads();
    int prefix = 0;
    for (int w = 0; w < wid; ++w) prefix += wt[w];
    int texcl = prefix + incl - s + blk_offs[blockIdx.x];
    #pragma unroll
    for (int i = 0; i < SCAN_ITEMS; ++i) {
        int idx = base + i;
        if (idx < n) row_ptr[idx] = texcl + vals[i];
    }
}

__global__ __launch_bounds__(1024) void init_bcur_kernel(const int* __restrict__ row_ptr,
                                                         int* __restrict__ bcur, int nb, int n) {
    int b = threadIdx.x;
    if (b < nb) {
        int node = b << NB_SHIFT;
        if (node > n) node = n;
        bcur[b] = row_ptr[node];
    }
}

__global__ __launch_bounds__(256) void bin_edges_kernel(const int* __restrict__ ei, int E,
                                                        int* __restrict__ bcur,
                                                        int2* __restrict__ pairs, int nb) {
    __shared__ int hist[1024];
    __shared__ int base[1024];
    const int tid = threadIdx.x;
    for (int i = tid; i < nb; i += 256) hist[i] = 0;
    __syncthreads();

    int e0 = blockIdx.x * BIN_CHUNK;
    int s_r[BIN_EPT], d_r[BIN_EPT], idx_r[BIN_EPT];
    #pragma unroll
    for (int i = 0; i < BIN_EPT; ++i) {
        int e = e0 + i * 256 + tid;
        if (e < E) {
            s_r[i] = ei[e];
            d_r[i] = ei[E + e];
            idx_r[i] = atomicAdd(&hist[d_r[i] >> NB_SHIFT], 1);
        }
    }
    __syncthreads();
    for (int i = tid; i < nb; i += 256) {
        int c = hist[i];
        base[i] = c ? atomicAdd(&bcur[i], c) : 0;
    }
    __syncthreads();
    #pragma unroll
    for (int i = 0; i < BIN_EPT; ++i) {
        int e = e0 + i * 256 + tid;
        if (e < E) {
            int pos = base[d_r[i] >> NB_SHIFT] + idx_r[i];
            pairs[pos] = make_int2(s_r[i], d_r[i]);
        }
    }
}

__global__ __launch_bounds__(256) void csr_fill_binned(const int2* __restrict__ pairs, int E,
                                                       const int* __restrict__ row_ptr,
                                                       int* __restrict__ cursor,
                                                       int* __restrict__ csr_src) {
    int e = blockIdx.x * 256 + threadIdx.x;
    if (e >= E) return;
    int2 p = pairs[e];
    int pos = row_ptr[p.y] + atomicAdd(&cursor[p.y], 1);
    csr_src[pos] = p.x;
}

// ---------------- aggregation (bf16 gather, fp32 accum, bf16 out) ----------------
__global__ __launch_bounds__(256) void aggregate_bf16(const ushort_t* __restrict__ h,
                                                      const int* __restrict__ row_ptr,
                                                      const int* __restrict__ csr_src,
                                                      ushort_t* __restrict__ agg, int n) {
    int node = blockIdx.x * 16 + (threadIdx.x >> 4);
    int lane = threadIdx.x & 15;
    if (node >= n) return;
    int s0 = row_ptr[node];
    int s1 = row_ptr[node + 1];
    float acc[8] = {0.f, 0.f, 0.f, 0.f, 0.f, 0.f, 0.f, 0.f};
    int e = s0;
    for (; e + 4 <= s1; e += 4) {
        int i0 = csr_src[e];
        int i1 = csr_src[e + 1];
        int i2 = csr_src[e + 2];
        int i3 = csr_src[e + 3];
        u16x8 v0 = *(const u16x8*)&h[(size_t)i0 * D + lane * 8];
        u16x8 v1 = *(const u16x8*)&h[(size_t)i1 * D + lane * 8];
        u16x8 v2 = *(const u16x8*)&h[(size_t)i2 * D + lane * 8];
        u16x8 v3 = *(const u16x8*)&h[(size_t)i3 * D + lane * 8];
        #pragma unroll
        for (int i = 0; i < 8; ++i)
            acc[i] += bf2f(v0[i]) + bf2f(v1[i]) + bf2f(v2[i]) + bf2f(v3[i]);
    }
    for (; e < s1; ++e) {
        int src = csr_src[e];
        u16x8 v = *(const u16x8*)&h[(size_t)src * D + lane * 8];
        #pragma unroll
        for (int i = 0; i < 8; ++i) acc[i] += bf2f(v[i]);
    }
    int dg = s1 - s0;
    float sc = (dg > 0) ? (1.0f / (float)dg) : 0.0f;
    u16x8 o;
    #pragma unroll
    for (int i = 0; i < 8; ++i) o[i] = f2bf(acc[i] * sc);
    *(u16x8*)&agg[(size_t)node * D + lane * 8] = o;
}

// ---------------- fused SAGE layer: MFMA GEMM + bias + LN + SiLU ----------------
// Block = 4 waves, 64 rows x 128 cols. Wave w owns cols [w*32, w*32+32) for ALL
// 64 rows; its 16 B-fragments (2 jt x 8 k-chunks) are hoisted into registers,
// so the K-loop is 4 A-loads + 8 MFMAs per chunk (B-traffic /4 vs per-wave-128-col).
// LN reduces across waves via 2 KB of LDS partials.
__global__ __launch_bounds__(256) void sage_mfma(
    const ushort_t* __restrict__ agg, const ushort_t* __restrict__ hin,
    const ushort_t* __restrict__ Wl, const ushort_t* __restrict__ Wr,
    const float* __restrict__ bl, const float* __restrict__ br,
    const float* __restrict__ lng, const float* __restrict__ lnb,
    ushort_t* __restrict__ hout, int n) {
    __shared__ float part_s[64][4];
    __shared__ float part_s2[64][4];
    __shared__ ushort_t tile[64][132];

    const int tid = threadIdx.x;
    const int w = tid >> 6;           // wave 0..3
    const int lane = tid & 63;
    const int quad = lane >> 4;       // 0..3 (k-offset for A/B frags; row-quad for C)
    const int l16 = lane & 15;
    const int n0 = blockIdx.x * 64;

    // clamped A-row indices for the 4 row-tiles
    int arow[4];
    #pragma unroll
    for (int rt = 0; rt < 4; ++rt) {
        int r = n0 + rt * 16 + l16;
        arow[rt] = (r < n) ? r : (n - 1);
    }

    // hoist this wave's B fragments: 2 jt x 8 chunks
    bf16x8 bfrag[8][2];
    #pragma unroll
    for (int c = 0; c < 8; ++c) {
        const ushort_t* __restrict__ W = (c < 4) ? Wl : Wr;
        const int kb = (c & 3) * 32;
        #pragma unroll
        for (int jl = 0; jl < 2; ++jl) {
            int j = (2 * w + jl) * 16 + l16;
            bfrag[c][jl] = *(const bf16x8*)&W[(size_t)j * D + kb + quad * 8];
        }
    }

    f32x4 acc[4][2];
    #pragma unroll
    for (int rt = 0; rt < 4; ++rt)
        #pragma unroll
        for (int jl = 0; jl < 2; ++jl) acc[rt][jl] = (f32x4){0.f, 0.f, 0.f, 0.f};

    #pragma unroll
    for (int c = 0; c < 8; ++c) {
        const ushort_t* __restrict__ act = (c < 4) ? agg : hin;
        const int kb = (c & 3) * 32;
        bf16x8 af[4];
        #pragma unroll
        for (int rt = 0; rt < 4; ++rt)
            af[rt] = *(const bf16x8*)&act[(size_t)arow[rt] * D + kb + quad * 8];
        #pragma unroll
        for (int rt = 0; rt < 4; ++rt)
            #pragma unroll
            for (int jl = 0; jl < 2; ++jl)
                acc[rt][jl] = __builtin_amdgcn_mfma_f32_16x16x32_bf16(af[rt], bfrag[c][jl],
                                                                      acc[rt][jl], 0, 0, 0);
    }

    // epilogue: bias, cross-wave LN partials
    float bsum[2], g[2], bb[2];
    #pragma unroll
    for (int jl = 0; jl < 2; ++jl) {
        int j = (2 * w + jl) * 16 + l16;
        bsum[jl] = bl[j] + br[j];
        g[jl] = lng[j];
        bb[jl] = lnb[j];
    }
    #pragma unroll
    for (int rt = 0; rt < 4; ++rt) {
        #pragma unroll
        for (int r = 0; r < 4; ++r) {
            float v0 = acc[rt][0][r] + bsum[0];
            float v1 = acc[rt][1][r] + bsum[1];
            acc[rt][0][r] = v0;
            acc[rt][1][r] = v1;
            float s = v0 + v1;
            float s2 = v0 * v0 + v1 * v1;
            #pragma unroll
            for (int off = 1; off < 16; off <<= 1) {
                s += __shfl_xor(s, off, 64);
                s2 += __shfl_xor(s2, off, 64);
            }
            if (l16 == 0) {
                int row = rt * 16 + quad * 4 + r;
                part_s[row][w] = s;
                part_s2[row][w] = s2;
            }
        }
    }
    __syncthreads();
    #pragma unroll
    for (int rt = 0; rt < 4; ++rt) {
        #pragma unroll
        for (int r = 0; r < 4; ++r) {
            int row = rt * 16 + quad * 4 + r;
            float s = part_s[row][0] + part_s[row][1] + part_s[row][2] + part_s[row][3];
            float s2 = part_s2[row][0] + part_s2[row][1] + part_s2[row][2] + part_s2[row][3];
            float mean = s * (1.0f / 128.0f);
            float var = s2 * (1.0f / 128.0f) - mean * mean;
            float rstd = rsqrtf(var + LN_EPS);
            #pragma unroll
            for (int jl = 0; jl < 2; ++jl) {
                float z = (acc[rt][jl][r] - mean) * rstd * g[jl] + bb[jl];
                float sv = z / (1.0f + expf(-z));
                tile[row][(2 * w + jl) * 16 + l16] = f2bf(sv);
            }
        }
    }
    __syncthreads();
    int row = tid >> 2, seg = tid & 3;
    int node = n0 + row;
    if (node < n) {
        #pragma unroll
        for (int k2 = 0; k2 < 4; ++k2) {
            u16x8 vv = *(const u16x8*)&tile[row][seg * 32 + k2 * 8];
            *(u16x8*)&hout[(size_t)node * D + seg * 32 + k2 * 8] = vv;
        }
    }
}

// ---------------- fused MLP head: same wave mapping; ReLU + dot(w2) epilogue ----
__global__ __launch_bounds__(256) void mlp_head_mfma(
    const ushort_t* __restrict__ hin, const ushort_t* __restrict__ W1,
    const float* __restrict__ b1, const float* __restrict__ w2,
    const float* __restrict__ b2, float* __restrict__ out, int n) {
    __shared__ float part[64][4];

    const int tid = threadIdx.x;
    const int w = tid >> 6;
    const int lane = tid & 63;
    const int quad = lane >> 4;
    const int l16 = lane & 15;
    const int n0 = blockIdx.x * 64;

    int arow[4];
    #pragma unroll
    for (int rt = 0; rt < 4; ++rt) {
        int r = n0 + rt * 16 + l16;
        arow[rt] = (r < n) ? r : (n - 1);
    }

    bf16x8 bfrag[4][2];
    #pragma unroll
    for (int c = 0; c < 4; ++c) {
        const int kb = c * 32;
        #pragma unroll
        for (int jl = 0; jl < 2; ++jl) {
            int j = (2 * w + jl) * 16 + l16;
            bfrag[c][jl] = *(const bf16x8*)&W1[(size_t)j * D + kb + quad * 8];
        }
    }

    f32x4 acc[4][2];
    #pragma unroll
    for (int rt = 0; rt < 4; ++rt)
        #pragma unroll
        for (int jl = 0; jl < 2; ++jl) acc[rt][jl] = (f32x4){0.f, 0.f, 0.f, 0.f};

    #pragma unroll
    for (int c = 0; c < 4; ++c) {
        const int kb = c * 32;
        bf16x8 af[4];
        #pragma unroll
        for (int rt = 0; rt < 4; ++rt)
            af[rt] = *(const bf16x8*)&hin[(size_t)arow[rt] * D + kb + quad * 8];
        #pragma unroll
        for (int rt = 0; rt < 4; ++rt)
            #pragma unroll
            for (int jl = 0; jl < 2; ++jl)
                acc[rt][jl] = __builtin_amdgcn_mfma_f32_16x16x32_bf16(af[rt], bfrag[c][jl],
                                                                      acc[rt][jl], 0, 0, 0);
    }

    float bias1[2], wv2[2];
    #pragma unroll
    for (int jl = 0; jl < 2; ++jl) {
        int j = (2 * w + jl) * 16 + l16;
        bias1[jl] = b1[j];
        wv2[jl] = w2[j];
    }
    #pragma unroll
    for (int rt = 0; rt < 4; ++rt) {
        #pragma unroll
        for (int r = 0; r < 4; ++r) {
            float p = fmaxf(acc[rt][0][r] + bias1[0], 0.0f) * wv2[0]
                    + fmaxf(acc[rt][1][r] + bias1[1], 0.0f) * wv2[1];
            #pragma unroll
            for (int off = 1; off < 16; off <<= 1) p += __shfl_xor(p, off, 64);
            if (l16 == 0) part[rt * 16 + quad * 4 + r][w] = p;
        }
    }
    __syncthreads();
    if (tid < 64) {
        int node = n0 + tid;
        if (node < n)
            out[node] = part[tid][0] + part[tid][1] + part[tid][2] + part[tid][3] + b2[0];
    }
}

// ---------------- launch ----------------
static inline size_t align_up(size_t v, size_t a) { return (v + a - 1) & ~(a - 1); }

extern "C" void kernel_launch(void* const* d_in, const int* in_sizes, int n_in,
                              void* d_out, int out_size, void* d_ws, size_t ws_size,
                              hipStream_t stream) {
    const float* x       = (const float*)d_in[0];
    const int*   ei      = (const int*)d_in[1];
    const float* lin_l_w = (const float*)d_in[2];
    const float* lin_l_b = (const float*)d_in[3];
    const float* lin_r_w = (const float*)d_in[4];
    const float* lin_r_b = (const float*)d_in[5];
    const float* ln_g    = (const float*)d_in[6];
    const float* ln_b    = (const float*)d_in[7];
    const float* mlp_w1  = (const float*)d_in[8];
    const float* mlp_b1  = (const float*)d_in[9];
    const float* mlp_w2  = (const float*)d_in[10];
    const float* mlp_b2  = (const float*)d_in[11];
    float* out = (float*)d_out;

    const int N = in_sizes[0] / D;   // 100000
    const int E = in_sizes[1] / 2;   // 1600000
    const int NB = (N + (1 << NB_SHIFT) - 1) >> NB_SHIFT;   // 782

    // workspace layout
    char* w = (char*)d_ws;
    size_t off = 0;
    int* deg = (int*)(w + off);        off = align_up(off + sizeof(int) * (size_t)N, 512);
    int* row_ptr = (int*)(w + off);    off = align_up(off + sizeof(int) * (size_t)(N + 1), 512);
    int* cursor = (int*)(w + off);     off = align_up(off + sizeof(int) * (size_t)N, 512);
    int* blk_sums = (int*)(w + off);   off = align_up(off + sizeof(int) * 1024, 512);
    int* bcur = (int*)(w + off);       off = align_up(off + sizeof(int) * 1024, 512);
    int* csr_src = (int*)(w + off);    off = align_up(off + sizeof(int) * (size_t)E, 512);
    int2* pairs = (int2*)(w + off);    off = align_up(off + sizeof(int2) * (size_t)E, 512);
    ushort_t* x_bf = (ushort_t*)(w + off);   off = align_up(off + 2ull * N * D, 512);
    ushort_t* h1_bf = (ushort_t*)(w + off);  off = align_up(off + 2ull * N * D, 512);
    ushort_t* h2_bf = (ushort_t*)(w + off);  off = align_up(off + 2ull * N * D, 512);
    ushort_t* agg_bf = (ushort_t*)(w + off); off = align_up(off + 2ull * N * D, 512);
    ushort_t* wl_bf = (ushort_t*)(w + off);  off = align_up(off + 2ull * 2 * D * D, 512);
    ushort_t* wr_bf = (ushort_t*)(w + off);  off = align_up(off + 2ull * 2 * D * D, 512);
    ushort_t* w1_bf = (ushort_t*)(w + off);  off = align_up(off + 2ull * D * D, 512);

    hipMemsetAsync(deg, 0, sizeof(int) * (size_t)N, stream);
    hipMemsetAsync(cursor, 0, sizeof(int) * (size_t)N, stream);

    // weight + input casts (bf16)
    cast_f32_bf16<<<(2 * D * D) / (8 * 256), 256, 0, stream>>>(lin_l_w, wl_bf, 2 * D * D);
    cast_f32_bf16<<<(2 * D * D) / (8 * 256), 256, 0, stream>>>(lin_r_w, wr_bf, 2 * D * D);
    cast_f32_bf16<<<(D * D + 8 * 256 - 1) / (8 * 256), 256, 0, stream>>>(mlp_w1, w1_bf, D * D);
    cast_f32_bf16<<<(N * D) / (8 * 256), 256, 0, stream>>>(x, x_bf, N * D);

    // graph build
    degree_kernel<<<(E + 255) / 256, 256, 0, stream>>>(ei, E, deg);
    const int nb_scan = (N + SCAN_CHUNK - 1) / SCAN_CHUNK;
    block_sum_kernel<<<nb_scan, SCAN_BLOCK, 0, stream>>>(deg, blk_sums, N);
    scan_sums_kernel<<<1, 1024, 0, stream>>>(blk_sums, nb_scan, row_ptr, N);
    scan_chunk_kernel<<<nb_scan, SCAN_BLOCK, 0, stream>>>(deg, blk_sums, row_ptr, N);
    init_bcur_kernel<<<1, 1024, 0, stream>>>(row_ptr, bcur, NB, N);
    bin_edges_kernel<<<(E + BIN_CHUNK - 1) / BIN_CHUNK, 256, 0, stream>>>(ei, E, bcur, pairs, NB);
    csr_fill_binned<<<(E + 255) / 256, 256, 0, stream>>>(pairs, E, row_ptr, cursor, csr_src);

    const int gemm_grid = (N + 63) / 64;
    const int agg_grid = (N + 15) / 16;

    // layer 0
    aggregate_bf16<<<agg_grid, 256, 0, stream>>>(x_bf, row_ptr, csr_src, agg_bf, N);
    sage_mfma<<<gemm_grid, 256, 0, stream>>>(
        agg_bf, x_bf, wl_bf, wr_bf, lin_l_b, lin_r_b, ln_g, ln_b, h1_bf, N);
    // layer 1
    aggregate_bf16<<<agg_grid, 256, 0, stream>>>(h1_bf, row_ptr, csr_src, agg_bf, N);
    sage_mfma<<<gemm_grid, 256, 0, stream>>>(
        agg_bf, h1_bf, wl_bf + D * D, wr_bf + D * D, lin_l_b + D, lin_r_b + D,
        ln_g + D, ln_b + D, h2_bf, N);
    // head
    mlp_head_mfma<<<gemm_grid, 256, 0, stream>>>(h2_bf, w1_bf, mlp_b1, mlp_w2, mlp_b2, out, N);
}